// Round 1
// baseline (187.924 us; speedup 1.0000x reference)
//
#include <hip/hip_runtime.h>
#include <hip/hip_bf16.h>

// Problem constants (derived from in_sizes at launch where possible)
// N=10000 nodes, F=256, H=256, E=320000 edges.

// ---------------------------------------------------------------------------
// Kernel 0: transpose/pack W1 (H=256, 2F=512) row-major into Wt[k][n] with
// n in [0,512): n<256 -> W1a column (W1[n][k]), n>=256 -> W1b (W1[n-256][256+k]).
// Coalesced writes; scattered reads of a 512KB L2-resident matrix (cheap).
// ---------------------------------------------------------------------------
__global__ __launch_bounds__(256) void transpose_w(const float* __restrict__ W1,
                                                   float* __restrict__ Wt) {
    int idx = blockIdx.x * 256 + threadIdx.x;      // 0 .. 131071
    int n = idx & 511;
    int k = idx >> 9;
    int h = n & 255;
    int koff = (n >> 8) << 8;                      // 0 or 256
    Wt[idx] = W1[(size_t)h * 512 + koff + k];
}

// ---------------------------------------------------------------------------
// Kernel 1: uv[m][n] = sum_k x[m][k] * Wt[k][n],  M=10000, N=512, K=256.
// 64x64 tile per 256-thread block, 4x4 accum per thread, K-tile = 16.
// ---------------------------------------------------------------------------
__global__ __launch_bounds__(256) void gemm_uv(const float* __restrict__ x,
                                               const float* __restrict__ Wt,
                                               float* __restrict__ uv, int M) {
    __shared__ float As[16][64];   // [k][m]
    __shared__ float Bs[16][64];   // [k][n]

    const int t  = threadIdx.x;
    const int bm = blockIdx.x;
    const int bn = blockIdx.y;     // 0..7
    const int tx = t & 15;         // col group -> cols tx*4 .. +3
    const int ty = t >> 4;         // row group -> rows ty*4 .. +3

    // A-tile load mapping: thread t loads float4 at row (t>>2), k-offset (t&3)*4
    const int arow  = t >> 2;          // 0..63
    const int akoff = (t & 3) * 4;     // 0,4,8,12
    const int grow_a = bm * 64 + arow;
    const bool avalid = grow_a < M;
    const float* xrow = x + (size_t)grow_a * 256 + akoff;

    // B-tile load mapping: thread t loads float4 at k=(t>>4), n-offset (t&15)*4
    const int brow = t >> 4;           // 0..15
    const int bcol = (t & 15) * 4;
    const float* wrow = Wt + (size_t)brow * 512 + bn * 64 + bcol;

    float acc[4][4];
#pragma unroll
    for (int i = 0; i < 4; ++i)
#pragma unroll
        for (int j = 0; j < 4; ++j) acc[i][j] = 0.f;

    for (int kt = 0; kt < 256; kt += 16) {
        float4 av = avalid ? *(const float4*)(xrow + kt)
                           : float4{0.f, 0.f, 0.f, 0.f};
        float4 bv = *(const float4*)(wrow + (size_t)kt * 512);

        __syncthreads();   // previous iteration's reads complete
        As[akoff + 0][arow] = av.x;
        As[akoff + 1][arow] = av.y;
        As[akoff + 2][arow] = av.z;
        As[akoff + 3][arow] = av.w;
        *(float4*)&Bs[brow][bcol] = bv;
        __syncthreads();

#pragma unroll
        for (int kk = 0; kk < 16; ++kk) {
            float4 a4 = *(const float4*)&As[kk][ty * 4];
            float4 b4 = *(const float4*)&Bs[kk][tx * 4];
            float a_[4] = {a4.x, a4.y, a4.z, a4.w};
            float b_[4] = {b4.x, b4.y, b4.z, b4.w};
#pragma unroll
            for (int i = 0; i < 4; ++i)
#pragma unroll
                for (int j = 0; j < 4; ++j) acc[i][j] += a_[i] * b_[j];
        }
    }

    const int grow = bm * 64 + ty * 4;
    const int gcol = bn * 64 + tx * 4;
#pragma unroll
    for (int i = 0; i < 4; ++i) {
        if (grow + i < M) {
            float4 o = {acc[i][0], acc[i][1], acc[i][2], acc[i][3]};
            *(float4*)&uv[(size_t)(grow + i) * 512 + gcol] = o;
        }
    }
}

// ---------------------------------------------------------------------------
// Kernel 2: per edge e: out[e] = sigmoid( b2 + sum_j relu(U[row][j]+V[col][j]+b1[j])*W2[j] )
// One wave per edge; lane i owns j = 4i..4i+3 (float4). Wave shuffle reduce.
// uv layout: uv[node][0:256] = U, uv[node][256:512] = V.
// ---------------------------------------------------------------------------
__global__ __launch_bounds__(256) void edge_kernel(const float* __restrict__ uv,
                                                   const int* __restrict__ ei,
                                                   const float* __restrict__ b1,
                                                   const float* __restrict__ w2,
                                                   const float* __restrict__ b2p,
                                                   float* __restrict__ out, int E) {
    const int tid   = blockIdx.x * blockDim.x + threadIdx.x;
    const int lane  = threadIdx.x & 63;
    const int wave  = tid >> 6;
    const int nwav  = (gridDim.x * blockDim.x) >> 6;

    const float4 b1v = *(const float4*)(b1 + lane * 4);
    const float4 w2v = *(const float4*)(w2 + lane * 4);
    const float  b2  = b2p[0];

    for (int e = wave; e < E; e += nwav) {
        const int row = ei[e];
        const int col = ei[E + e];
        float4 u = *(const float4*)(uv + (size_t)row * 512 + lane * 4);
        float4 v = *(const float4*)(uv + (size_t)col * 512 + 256 + lane * 4);

        float p;
        p  = fmaxf(u.x + v.x + b1v.x, 0.f) * w2v.x;
        p += fmaxf(u.y + v.y + b1v.y, 0.f) * w2v.y;
        p += fmaxf(u.z + v.z + b1v.z, 0.f) * w2v.z;
        p += fmaxf(u.w + v.w + b1v.w, 0.f) * w2v.w;

#pragma unroll
        for (int off = 32; off >= 1; off >>= 1)
            p += __shfl_down(p, off, 64);

        if (lane == 0) {
            float logit = p + b2;
            out[e] = 1.f / (1.f + __expf(-logit));
        }
    }
}

extern "C" void kernel_launch(void* const* d_in, const int* in_sizes, int n_in,
                              void* d_out, int out_size, void* d_ws, size_t ws_size,
                              hipStream_t stream) {
    const float* x  = (const float*)d_in[0];
    const int*   ei = (const int*)d_in[1];
    const float* W1 = (const float*)d_in[2];
    const float* b1 = (const float*)d_in[3];
    const float* W2 = (const float*)d_in[4];
    const float* b2 = (const float*)d_in[5];
    float* out = (float*)d_out;

    const int N = in_sizes[0] / 256;   // 10000
    const int E = in_sizes[1] / 2;     // 320000

    float* uv = (float*)d_ws;                       // N * 512 floats (~20.5 MB)
    float* Wt = uv + (size_t)N * 512;               // 256*512 floats (512 KB)

    transpose_w<<<512, 256, 0, stream>>>(W1, Wt);

    dim3 g((N + 63) / 64, 8);
    gemm_uv<<<g, 256, 0, stream>>>(x, Wt, uv, N);

    edge_kernel<<<2048, 256, 0, stream>>>(uv, ei, b1, W2, b2, out, E);
}

// Round 2
// 142.171 us; speedup vs baseline: 1.3218x; 1.3218x over previous
//
#include <hip/hip_runtime.h>
#include <hip/hip_bf16.h>

// N=10000 nodes, F=256, H=256, E=320000 edges.
//
// Decomposition: W1 = [W1a | W1b] (each Hx256).
//   U = x @ W1a^T, V = x @ W1b^T   (per-node, bf16 MFMA GEMM)
//   out[e] = sigmoid(b2 + sum_j relu(U[row][j] + V[col][j] + b1[j]) * W2[j])
// uv layout: uv[node][0:256]=U, uv[node][256:512]=V, bf16 (1 KB/row).

typedef __attribute__((ext_vector_type(8))) short bf16x8;
typedef __attribute__((ext_vector_type(4))) float f32x4;

__device__ __forceinline__ unsigned short f2bf(float f) {
    __hip_bfloat16 h = __float2bfloat16(f);
    return *reinterpret_cast<unsigned short*>(&h);
}
__device__ __forceinline__ float bf2f(unsigned short u) {
    return __uint_as_float(((unsigned int)u) << 16);
}

// ---------------------------------------------------------------------------
// Kernel 0: convert x (nx4*4 floats) and W1 (nw4*4 floats) to bf16.
// ---------------------------------------------------------------------------
__global__ __launch_bounds__(256) void convert_bf16(const float* __restrict__ x,
                                                    const float* __restrict__ w1,
                                                    unsigned short* __restrict__ xb,
                                                    unsigned short* __restrict__ wb,
                                                    int nx4, int nw4) {
    int i = blockIdx.x * 256 + threadIdx.x;
    if (i < nx4) {
        float4 v = ((const float4*)x)[i];
        ushort4 o = {f2bf(v.x), f2bf(v.y), f2bf(v.z), f2bf(v.w)};
        ((ushort4*)xb)[i] = o;
    } else if (i < nx4 + nw4) {
        int j = i - nx4;
        float4 v = ((const float4*)w1)[j];
        ushort4 o = {f2bf(v.x), f2bf(v.y), f2bf(v.z), f2bf(v.w)};
        ((ushort4*)wb)[j] = o;
    }
}

// ---------------------------------------------------------------------------
// Kernel 1: uv[m][n] = sum_k xb[m][k] * W1bf[n&255][(n>=256)*256 + k]
// MFMA 16x16x32 bf16. One wave -> 16(M) x 64(N); block = 4 waves -> 64x64.
// W1 natural (256 x 512) layout IS the B-fragment layout (8 contiguous k/lane).
// A-frag: xb[m0 + (lane&15)][kt + (lane>>4)*8 .. +7]  (16B contiguous load).
// C/D:    col = lane&15, row = (lane>>4)*4 + reg.
// ---------------------------------------------------------------------------
__global__ __launch_bounds__(256) void gemm_mfma(const unsigned short* __restrict__ xb,
                                                 const unsigned short* __restrict__ wb,
                                                 unsigned short* __restrict__ uv,
                                                 int M) {
    const int wave = threadIdx.x >> 6;
    const int lane = threadIdx.x & 63;
    const int mtile = blockIdx.x * 4 + wave;          // 16-row tile index
    if (mtile * 16 >= M) return;
    const int n0 = blockIdx.y * 64;                   // 0..448, uniform half
    const int koff = (n0 >= 256) ? 256 : 0;
    const int nbase = n0 & 255;                       // W1 row base

    const int lm = lane & 15;
    const int lk = (lane >> 4) * 8;

    const unsigned short* aptr = xb + (size_t)(mtile * 16 + lm) * 256 + lk;
    const unsigned short* bptr = wb + (size_t)(nbase + lm) * 512 + koff + lk;

    f32x4 acc0 = {0.f, 0.f, 0.f, 0.f};
    f32x4 acc1 = {0.f, 0.f, 0.f, 0.f};
    f32x4 acc2 = {0.f, 0.f, 0.f, 0.f};
    f32x4 acc3 = {0.f, 0.f, 0.f, 0.f};

#pragma unroll
    for (int kt = 0; kt < 256; kt += 32) {
        bf16x8 a  = *(const bf16x8*)(aptr + kt);
        bf16x8 b0 = *(const bf16x8*)(bptr + kt);
        bf16x8 b1 = *(const bf16x8*)(bptr + 16 * 512 + kt);
        bf16x8 b2 = *(const bf16x8*)(bptr + 32 * 512 + kt);
        bf16x8 b3 = *(const bf16x8*)(bptr + 48 * 512 + kt);
        acc0 = __builtin_amdgcn_mfma_f32_16x16x32_bf16(a, b0, acc0, 0, 0, 0);
        acc1 = __builtin_amdgcn_mfma_f32_16x16x32_bf16(a, b1, acc1, 0, 0, 0);
        acc2 = __builtin_amdgcn_mfma_f32_16x16x32_bf16(a, b2, acc2, 0, 0, 0);
        acc3 = __builtin_amdgcn_mfma_f32_16x16x32_bf16(a, b3, acc3, 0, 0, 0);
    }

    const int row0 = mtile * 16 + (lane >> 4) * 4;
    f32x4 accs[4] = {acc0, acc1, acc2, acc3};
#pragma unroll
    for (int nt = 0; nt < 4; ++nt) {
        const size_t cbase = n0 + nt * 16 + lm;
#pragma unroll
        for (int r = 0; r < 4; ++r) {
            uv[(size_t)(row0 + r) * 512 + cbase] = f2bf(accs[nt][r]);
        }
    }
}

// ---------------------------------------------------------------------------
// Kernel 2: one wave per edge; lane i owns j = 4i..4i+3.
// uv rows are bf16: lane loads ushort4 (8B) from U half and V half.
// ---------------------------------------------------------------------------
__global__ __launch_bounds__(256) void edge_kernel(const unsigned short* __restrict__ uv,
                                                   const int* __restrict__ ei,
                                                   const float* __restrict__ b1,
                                                   const float* __restrict__ w2,
                                                   const float* __restrict__ b2p,
                                                   float* __restrict__ out, int E) {
    const int tid  = blockIdx.x * blockDim.x + threadIdx.x;
    const int lane = threadIdx.x & 63;
    const int wave = tid >> 6;
    const int nwav = (gridDim.x * blockDim.x) >> 6;

    const float4 b1v = *(const float4*)(b1 + lane * 4);
    const float4 w2v = *(const float4*)(w2 + lane * 4);
    const float  b2  = b2p[0];

    for (int e = wave; e < E; e += nwav) {
        const int row = ei[e];
        const int col = ei[E + e];
        ushort4 ur = *(const ushort4*)(uv + (size_t)row * 512 + lane * 4);
        ushort4 vr = *(const ushort4*)(uv + (size_t)col * 512 + 256 + lane * 4);

        float p;
        p  = fmaxf(bf2f(ur.x) + bf2f(vr.x) + b1v.x, 0.f) * w2v.x;
        p += fmaxf(bf2f(ur.y) + bf2f(vr.y) + b1v.y, 0.f) * w2v.y;
        p += fmaxf(bf2f(ur.z) + bf2f(vr.z) + b1v.z, 0.f) * w2v.z;
        p += fmaxf(bf2f(ur.w) + bf2f(vr.w) + b1v.w, 0.f) * w2v.w;

#pragma unroll
        for (int off = 32; off >= 1; off >>= 1)
            p += __shfl_down(p, off, 64);

        if (lane == 0) {
            float logit = p + b2;
            out[e] = 1.f / (1.f + __expf(-logit));
        }
    }
}

extern "C" void kernel_launch(void* const* d_in, const int* in_sizes, int n_in,
                              void* d_out, int out_size, void* d_ws, size_t ws_size,
                              hipStream_t stream) {
    const float* x  = (const float*)d_in[0];
    const int*   ei = (const int*)d_in[1];
    const float* W1 = (const float*)d_in[2];
    const float* b1 = (const float*)d_in[3];
    const float* W2 = (const float*)d_in[4];
    const float* b2 = (const float*)d_in[5];
    float* out = (float*)d_out;

    const int N = in_sizes[0] / 256;   // 10000
    const int E = in_sizes[1] / 2;     // 320000

    unsigned short* uv = (unsigned short*)d_ws;            // N*512 bf16 (10.24 MB)
    unsigned short* xb = uv + (size_t)N * 512;             // N*256 bf16 (5.12 MB)
    unsigned short* wb = xb + (size_t)N * 256;             // 256*512 bf16 (256 KB)

    const int nx4 = (N * 256) / 4;         // 640000
    const int nw4 = (256 * 512) / 4;       // 32768
    const int nconv = nx4 + nw4;
    convert_bf16<<<(nconv + 255) / 256, 256, 0, stream>>>(x, W1, xb, wb, nx4, nw4);

    dim3 g((N / 16 + 3) / 4, 8);           // (157, 8): 64x64 per block
    gemm_mfma<<<g, 256, 0, stream>>>(xb, wb, uv, N);

    edge_kernel<<<2048, 256, 0, stream>>>(uv, ei, b1, W2, b2, out, E);
}

// Round 3
// 133.774 us; speedup vs baseline: 1.4048x; 1.0628x over previous
//
#include <hip/hip_runtime.h>
#include <hip/hip_bf16.h>

// N=10000 nodes, F=256, H=256, E=320000 edges.
//
// W1 = [W1a | W1b]:  U = x @ W1a^T, V = x @ W1b^T  (bf16 MFMA GEMM, fused x->bf16)
// out[e] = sigmoid(b2 + sum_j relu(U[row][j] + V[col][j] + b1[j]) * W2[j])
// uv layout: uv[node][0:256]=U, uv[node][256:512]=V, bf16 (1 KB/row).

typedef __attribute__((ext_vector_type(8))) short bf16x8;
typedef __attribute__((ext_vector_type(4))) float f32x4;

__device__ __forceinline__ unsigned short f2bf(float f) {
    __hip_bfloat16 h = __float2bfloat16(f);
    return *reinterpret_cast<unsigned short*>(&h);
}

// ---------------------------------------------------------------------------
// Kernel 0: convert W1 (256x512 fp32) to bf16. 32768 float4s — tiny.
// ---------------------------------------------------------------------------
__global__ __launch_bounds__(256) void convert_w(const float* __restrict__ w1,
                                                 unsigned short* __restrict__ wb,
                                                 int nw4) {
    int i = blockIdx.x * 256 + threadIdx.x;
    if (i < nw4) {
        float4 v = ((const float4*)w1)[i];
        ushort4 o = {f2bf(v.x), f2bf(v.y), f2bf(v.z), f2bf(v.w)};
        ((ushort4*)wb)[i] = o;
    }
}

// ---------------------------------------------------------------------------
// Kernel 1: uv[m][n] = sum_k x[m][k] * W1[n&255][(n>=256)*256 + k]
// MFMA 16x16x32 bf16; wave -> 16(M) x 64(N). x read as fp32, converted
// in-register (saves the x->bf16 roundtrip through HBM).
// A-frag: x[m0+(lane&15)][kt + (lane>>4)*8 .. +7]; B-frag = natural W1 rows.
// C/D: col=lane&15, row=(lane>>4)*4+reg.
// NOTE: unroll capped at 2 — full unroll put ~40 16B loads in flight and
// blew the VGPR budget (suspected spill, R2's hidden ~70us).
// ---------------------------------------------------------------------------
__global__ __launch_bounds__(256) void gemm_mfma(const float* __restrict__ x,
                                                 const unsigned short* __restrict__ wb,
                                                 unsigned short* __restrict__ uv,
                                                 int M) {
    const int wave = threadIdx.x >> 6;
    const int lane = threadIdx.x & 63;
    const int mtile = blockIdx.x * 4 + wave;          // 16-row tile index
    if (mtile * 16 >= M) return;
    const int n0 = blockIdx.y * 64;
    const int koff = (n0 >= 256) ? 256 : 0;
    const int nbase = n0 & 255;

    const int lm = lane & 15;
    const int lk = (lane >> 4) * 8;

    const float* aptr = x + (size_t)(mtile * 16 + lm) * 256 + lk;
    const unsigned short* bptr = wb + (size_t)(nbase + lm) * 512 + koff + lk;

    f32x4 acc0 = {0.f, 0.f, 0.f, 0.f};
    f32x4 acc1 = {0.f, 0.f, 0.f, 0.f};
    f32x4 acc2 = {0.f, 0.f, 0.f, 0.f};
    f32x4 acc3 = {0.f, 0.f, 0.f, 0.f};

#pragma unroll 2
    for (int kt = 0; kt < 256; kt += 32) {
        float4 alo = *(const float4*)(aptr + kt);
        float4 ahi = *(const float4*)(aptr + kt + 4);
        bf16x8 b0 = *(const bf16x8*)(bptr + kt);
        bf16x8 b1 = *(const bf16x8*)(bptr + 16 * 512 + kt);
        bf16x8 b2 = *(const bf16x8*)(bptr + 32 * 512 + kt);
        bf16x8 b3 = *(const bf16x8*)(bptr + 48 * 512 + kt);
        bf16x8 a;
        a[0] = (short)f2bf(alo.x); a[1] = (short)f2bf(alo.y);
        a[2] = (short)f2bf(alo.z); a[3] = (short)f2bf(alo.w);
        a[4] = (short)f2bf(ahi.x); a[5] = (short)f2bf(ahi.y);
        a[6] = (short)f2bf(ahi.z); a[7] = (short)f2bf(ahi.w);
        acc0 = __builtin_amdgcn_mfma_f32_16x16x32_bf16(a, b0, acc0, 0, 0, 0);
        acc1 = __builtin_amdgcn_mfma_f32_16x16x32_bf16(a, b1, acc1, 0, 0, 0);
        acc2 = __builtin_amdgcn_mfma_f32_16x16x32_bf16(a, b2, acc2, 0, 0, 0);
        acc3 = __builtin_amdgcn_mfma_f32_16x16x32_bf16(a, b3, acc3, 0, 0, 0);
    }

    const int row0 = mtile * 16 + (lane >> 4) * 4;
    f32x4 accs[4] = {acc0, acc1, acc2, acc3};
#pragma unroll
    for (int nt = 0; nt < 4; ++nt) {
        const size_t cbase = n0 + nt * 16 + lm;
#pragma unroll
        for (int r = 0; r < 4; ++r) {
            uv[(size_t)(row0 + r) * 512 + cbase] = f2bf(accs[nt][r]);
        }
    }
}

// ---------------------------------------------------------------------------
// Kernel 2: 4 edges per wave. Lane = (g = lane>>4: edge slot, c = lane&15:
// 16-col chunk). Per lane: 2x uint4 from U half, 2x uint4 from V half
// (32B each), lo/hi bf16 extraction, 4-step butterfly over the 16-lane group.
// ---------------------------------------------------------------------------
__global__ __launch_bounds__(256) void edge_kernel(const unsigned short* __restrict__ uv,
                                                   const int* __restrict__ ei,
                                                   const float* __restrict__ b1,
                                                   const float* __restrict__ w2,
                                                   const float* __restrict__ b2p,
                                                   float* __restrict__ out, int E) {
    const int lane = threadIdx.x & 63;
    const int g = lane >> 4;
    const int c = lane & 15;
    const int wid = (blockIdx.x * blockDim.x + threadIdx.x) >> 6;
    const int nwav = (gridDim.x * blockDim.x) >> 6;
    const int nb = E >> 2;   // batches of 4 edges (E % 4 == 0)

    float b1r[16], w2r[16];
#pragma unroll
    for (int i = 0; i < 4; ++i) {
        *(float4*)&b1r[i * 4] = *(const float4*)(b1 + c * 16 + i * 4);
        *(float4*)&w2r[i * 4] = *(const float4*)(w2 + c * 16 + i * 4);
    }
    const float b2 = b2p[0];

    for (int b = wid; b < nb; b += nwav) {
        const int e = b * 4 + g;
        const int row = ei[e];
        const int col = ei[E + e];
        const unsigned int* up = (const unsigned int*)(uv + (size_t)row * 512 + c * 16);
        const unsigned int* vp = (const unsigned int*)(uv + (size_t)col * 512 + 256 + c * 16);

        unsigned int uw[8], vw[8];
        *(uint4*)&uw[0] = *(const uint4*)up;
        *(uint4*)&uw[4] = *(const uint4*)(up + 4);
        *(uint4*)&vw[0] = *(const uint4*)vp;
        *(uint4*)&vw[4] = *(const uint4*)(vp + 4);

        float p = 0.f;
#pragma unroll
        for (int i = 0; i < 8; ++i) {
            float ulo = __uint_as_float(uw[i] << 16);
            float uhi = __uint_as_float(uw[i] & 0xffff0000u);
            float vlo = __uint_as_float(vw[i] << 16);
            float vhi = __uint_as_float(vw[i] & 0xffff0000u);
            float slo = fmaxf((ulo + vlo) + b1r[2 * i], 0.f);
            float shi = fmaxf((uhi + vhi) + b1r[2 * i + 1], 0.f);
            p = fmaf(slo, w2r[2 * i], p);
            p = fmaf(shi, w2r[2 * i + 1], p);
        }

#pragma unroll
        for (int off = 1; off < 16; off <<= 1)
            p += __shfl_xor(p, off, 64);

        if (c == 0) {
            out[e] = 1.f / (1.f + __expf(-(p + b2)));
        }
    }
}

extern "C" void kernel_launch(void* const* d_in, const int* in_sizes, int n_in,
                              void* d_out, int out_size, void* d_ws, size_t ws_size,
                              hipStream_t stream) {
    const float* x  = (const float*)d_in[0];
    const int*   ei = (const int*)d_in[1];
    const float* W1 = (const float*)d_in[2];
    const float* b1 = (const float*)d_in[3];
    const float* W2 = (const float*)d_in[4];
    const float* b2 = (const float*)d_in[5];
    float* out = (float*)d_out;

    const int N = in_sizes[0] / 256;   // 10000
    const int E = in_sizes[1] / 2;     // 320000

    unsigned short* uv = (unsigned short*)d_ws;        // N*512 bf16 (10.24 MB)
    unsigned short* wb = uv + (size_t)N * 512;         // 256*512 bf16 (256 KB)

    const int nw4 = (256 * 512) / 4;                   // 32768
    convert_w<<<(nw4 + 255) / 256, 256, 0, stream>>>(W1, wb, nw4);

    dim3 g((N / 16 + 3) / 4, 8);                       // (157, 8)
    gemm_mfma<<<g, 256, 0, stream>>>(x, wb, uv, N);

    edge_kernel<<<2048, 256, 0, stream>>>(uv, ei, b1, W2, b2, out, E);
}